// Round 7
// baseline (24517.892 us; speedup 1.0000x reference)
//
#include <hip/hip_runtime.h>
#include <hip/hip_bf16.h>

#define L_SEQ 2048
#define HDIM 512
#define NGATE4 2048   // 4*HD
#define TAGS 48
#define START_TAG 46
#define STOP_TAG 47
#define NWG 64        // workgroups per direction in lstm_layer

typedef float f32x4 __attribute__((ext_vector_type(4)));

// ---------------------------------------------------------------------------
// GEMM: C[M,N] = A[M,K] @ B[N,K]^T + bias1[n] (+ bias2[n])
// A rows optionally gathered: row m -> A + gather[m]*K (embedding lookup).
// f32 vector-ALU (no f32 MFMA on CDNA4). 64x64 tile, BK=32, 256 threads, 4x4/thread.
// ---------------------------------------------------------------------------
#define BM 64
#define BN 64
#define BK 32
#define LDT 68   // padded LDS row stride (floats)

__global__ __launch_bounds__(256, 2)
void gemm_abt(const float* __restrict__ A, const float* __restrict__ B,
              const float* __restrict__ bias1, const float* __restrict__ bias2,
              float* __restrict__ C, int M, int N, int K,
              const int* __restrict__ gather)
{
  __shared__ float As[BK][LDT];
  __shared__ float Bs[BK][LDT];
  const int tid = threadIdx.x;
  const int m0 = blockIdx.x * BM;
  const int n0 = blockIdx.y * BN;
  const int tm = tid >> 4, tn = tid & 15;
  const int lr = tid >> 2, lk = (tid & 3) * 8;

  float acc[4][4];
#pragma unroll
  for (int i = 0; i < 4; ++i)
#pragma unroll
    for (int c = 0; c < 4; ++c) acc[i][c] = 0.f;

  const int am = m0 + lr;
  const float* arow = gather ? (A + (size_t)gather[am] * (size_t)K)
                             : (A + (size_t)am * (size_t)K);
  const int bn = n0 + lr;
  const float* brow = B + (size_t)bn * (size_t)K;
  const bool bok = (bn < N);

  for (int kt = 0; kt < K; kt += BK) {
    const float4 a0 = *(const float4*)(arow + kt + lk);
    const float4 a1 = *(const float4*)(arow + kt + lk + 4);
    float4 b0 = make_float4(0.f, 0.f, 0.f, 0.f);
    float4 b1 = make_float4(0.f, 0.f, 0.f, 0.f);
    if (bok) {
      b0 = *(const float4*)(brow + kt + lk);
      b1 = *(const float4*)(brow + kt + lk + 4);
    }
    As[lk + 0][lr] = a0.x; As[lk + 1][lr] = a0.y; As[lk + 2][lr] = a0.z; As[lk + 3][lr] = a0.w;
    As[lk + 4][lr] = a1.x; As[lk + 5][lr] = a1.y; As[lk + 6][lr] = a1.z; As[lk + 7][lr] = a1.w;
    Bs[lk + 0][lr] = b0.x; Bs[lk + 1][lr] = b0.y; Bs[lk + 2][lr] = b0.z; Bs[lk + 3][lr] = b0.w;
    Bs[lk + 4][lr] = b1.x; Bs[lk + 5][lr] = b1.y; Bs[lk + 6][lr] = b1.z; Bs[lk + 7][lr] = b1.w;
    __syncthreads();
#pragma unroll
    for (int kk = 0; kk < BK; ++kk) {
      const float4 av = *(const float4*)&As[kk][tm * 4];
      const float4 bv = *(const float4*)&Bs[kk][tn * 4];
      const float aa[4] = {av.x, av.y, av.z, av.w};
      const float bb[4] = {bv.x, bv.y, bv.z, bv.w};
#pragma unroll
      for (int i = 0; i < 4; ++i)
#pragma unroll
        for (int c = 0; c < 4; ++c)
          acc[i][c] += aa[i] * bb[c];
    }
    __syncthreads();
  }

  float bsum[4];
#pragma unroll
  for (int c = 0; c < 4; ++c) {
    const int n = n0 + tn * 4 + c;
    float bb = 0.f;
    if (n < N) { bb = bias1[n]; if (bias2) bb += bias2[n]; }
    bsum[c] = bb;
  }
#pragma unroll
  for (int i = 0; i < 4; ++i) {
    const int m = m0 + tm * 4 + i;
#pragma unroll
    for (int c = 0; c < 4; ++c) {
      const int n = n0 + tn * 4 + c;
      if (n < N) C[(size_t)m * N + n] = acc[i][c] + bsum[c];
    }
  }
}

// ---------------------------------------------------------------------------
// Persistent bidirectional LSTM layer — weights resident in LDS.
// (r5/r6 lesson: the register allocator spills/remats 128-float register
// arrays no matter how they're phrased; LDS residency is architectural.)
// 64 WGs x 512 threads per direction (grid=128, all co-resident). Each WG
// owns 8 h-indices; weight slice = 8j x 4g x 512k x 4B = 64KB static LDS,
// staged once lane-major: wlds[wave][i][lane] -> per-step ds_read_b128 is
// conflict-free (consecutive lanes = consecutive 16B). Thread=(jj=wave,
// g=lane>>4, q=lane&15) computes a 32-k dot chunk; shfl-16 reduce; gate
// leaders add pre; lane0 gathers 4 gates, cell update, h store (agent
// atomics); slot release + 64-lane parallel acquire poll; h_lds refill.
// ---------------------------------------------------------------------------
__global__ __launch_bounds__(512, 1)
void lstm_layer(const float* __restrict__ pre_f, const float* __restrict__ pre_r,
                const float* __restrict__ whh_f, const float* __restrict__ whh_r,
                const float* __restrict__ h0, const float* __restrict__ c0,
                int hcrow_base,
                float* __restrict__ hs_out,   // [L][1024]
                int* __restrict__ slots)      // [2][NWG], zeroed before launch
{
  const int dir = blockIdx.x & 1;
  const int wg  = blockIdx.x >> 1;     // 0..63
  const float* pre = dir ? pre_r : pre_f;
  const float* whh = dir ? whh_r : whh_f;
  int* myslots = slots + dir * NWG;
  const int tid = threadIdx.x;
  const int lane = tid & 63;
  const int wave = tid >> 6;           // jj: owned h sub-index 0..7
  const int q = lane & 15;             // k-chunk 0..15 (32 k each)
  const int g = lane >> 4;             // gate 0..3
  const int j = wg * 8 + wave;         // owned h index
  const int hc = (hcrow_base + dir) * HDIM;

  __shared__ f32x4 wlds[8][8][64];     // [wave][i][lane] = 64 KB
  __shared__ float h_lds[HDIM];

  // Stage weights, lane-major. k-window rotated by q so per-step h_lds
  // reads land 2-way max on banks (free per m136).
  {
    const float* wr = whh + (size_t)(g * HDIM + j) * HDIM + 32 * q;
#pragma unroll
    for (int i = 0; i < 8; ++i)
      wlds[wave][i][lane] = *(const f32x4*)(wr + 4 * ((i + q) & 7));
  }
  h_lds[tid] = h0[hc + tid];           // blockDim == HDIM
  float cst = (lane == 0) ? c0[hc + j] : 0.f;
  __syncthreads();

  // pre-activation prefetch: one value per gate-leader lane (q == 0)
  float p = 0.f;
  if (q == 0) {
    const int t0 = dir ? (L_SEQ - 1) : 0;
    p = pre[(size_t)t0 * NGATE4 + g * HDIM + j];
  }

  for (int s = 0; s < L_SEQ; ++s) {
    const int t = dir ? (L_SEQ - 1 - s) : s;
    float pn = 0.f;
    if (q == 0 && (s + 1 < L_SEQ)) {
      const int tnx = dir ? (L_SEQ - 2 - s) : (s + 1);
      pn = pre[(size_t)tnx * NGATE4 + g * HDIM + j];
    }

    f32x4 acc = {0.f, 0.f, 0.f, 0.f};
#pragma unroll
    for (int i = 0; i < 8; ++i) {
      const f32x4 wv = wlds[wave][i][lane];
      const f32x4 hv = *(const f32x4*)&h_lds[32 * q + 4 * ((i + q) & 7)];
      acc += wv * hv;
    }
    float a = acc.x + acc.y + acc.z + acc.w;
#pragma unroll
    for (int m = 1; m < 16; m <<= 1) a += __shfl_xor(a, m, 64);
    a += p;                             // valid at gate-leader lanes (q==0)

    // gather the 4 gate sums (lanes 0,16,32,48) to every lane; lane0 updates
    const float a1 = __shfl(a, 16, 64);
    const float a2 = __shfl(a, 32, 64);
    const float a3 = __shfl(a, 48, 64);
    if (lane == 0) {
      const float si = 1.f / (1.f + __expf(-a));
      const float sf = 1.f / (1.f + __expf(-a1));
      const float tg = 1.f - 2.f / (__expf(2.f * a2) + 1.f);
      const float so = 1.f / (1.f + __expf(-a3));
      cst = sf * cst + si * tg;
      const float th = 1.f - 2.f / (__expf(2.f * cst) + 1.f);
      const float h = so * th;
      __hip_atomic_store(&hs_out[(size_t)t * 1024 + dir * HDIM + j], h,
                         __ATOMIC_RELAXED, __HIP_MEMORY_SCOPE_AGENT);
    }
    p = pn;

    if (s == L_SEQ - 1) break;

    __syncthreads();   // drains this WG's h store (vmcnt0 before barrier)
    if (tid == 0)
      __hip_atomic_store(&myslots[wg], s + 1, __ATOMIC_RELEASE,
                         __HIP_MEMORY_SCOPE_AGENT);
    if (wave == 0) {
      // 64 lanes poll 64 distinct slots; acquire rides the successful load
      for (;;) {
        const int v = __hip_atomic_load(&myslots[lane], __ATOMIC_ACQUIRE,
                                        __HIP_MEMORY_SCOPE_AGENT);
        if (__all(v > s)) break;
      }
    }
    __syncthreads();
    {
      const size_t base = (size_t)t * 1024 + dir * HDIM;
      h_lds[tid] = __hip_atomic_load(&hs_out[base + tid], __ATOMIC_RELAXED,
                                     __HIP_MEMORY_SCOPE_AGENT);
    }
    __syncthreads();
  }
}

// ---------------------------------------------------------------------------
// Viterbi: 1 WG, 192 threads = (48 tags) x (4 k-chunks of 12). Per step:
// chunk-local first-max chain, shfl argmax reduce over chunks (first-index
// tie-break matching jnp.argmax), fv via LDS. Backpointers to global ws;
// sequential backtrack at the end. Score -> out[0], path -> out[1..2048].
// ---------------------------------------------------------------------------
__global__ __launch_bounds__(192, 1)
void viterbi_kernel(const float* __restrict__ feats,
                    const float* __restrict__ trans,
                    int* __restrict__ bp,      // [L][48]
                    float* __restrict__ out)   // [1 + L]
{
  __shared__ float fv[TAGS];
  __shared__ float fvn[TAGS];
  const int tid = threadIdx.x;
  const int lane = tid & 63;
  const int wave = tid >> 6;
  const int q = lane & 3;
  const int j = wave * 16 + (lane >> 2);  // 0..47

  float trr[12];
#pragma unroll
  for (int kk = 0; kk < 12; ++kk) trr[kk] = trans[j * TAGS + q * 12 + kk];

  if (tid < TAGS) fv[tid] = (tid == START_TAG) ? 0.f : -10000.f;
  __syncthreads();

  for (int t = 0; t < L_SEQ; ++t) {
    const float ft = feats[t * TAGS + j];   // issued early, used post-reduce
    float best = -3.0e38f;
    int bi = 0;
#pragma unroll
    for (int kk = 0; kk < 12; ++kk) {
      const int k = q * 12 + kk;
      const float sc = fv[k] + trr[kk];
      if (sc > best) { best = sc; bi = k; }   // strict > keeps first max
    }
#pragma unroll
    for (int m = 1; m < 4; m <<= 1) {
      const float ov = __shfl_xor(best, m, 64);
      const int oi = __shfl_xor(bi, m, 64);
      if (ov > best || (ov == best && oi < bi)) { best = ov; bi = oi; }
    }
    __syncthreads();   // all fv reads done
    if (q == 0) {
      bp[t * TAGS + j] = bi;
      fv[j] = best + ft;
    }
    __syncthreads();
  }

  if (tid < TAGS) fvn[tid] = fv[tid] + trans[STOP_TAG * TAGS + tid];
  __syncthreads();
  if (tid == 0) {
    float best = -3.0e38f;
    int bi = 0;
    for (int k = 0; k < TAGS; ++k) {
      const float v = fvn[k];
      if (v > best) { best = v; bi = k; }
    }
    out[0] = best;
    int cur = bi;
    out[1 + (L_SEQ - 1)] = (float)cur;
    for (int t = L_SEQ - 2; t >= 0; --t) {
      cur = bp[(t + 1) * TAGS + cur];
      out[1 + t] = (float)cur;
    }
  }
}

// ---------------------------------------------------------------------------
extern "C" void kernel_launch(void* const* d_in, const int* in_sizes, int n_in,
                              void* d_out, int out_size, void* d_ws, size_t ws_size,
                              hipStream_t stream)
{
  const int*   sentence  = (const int*)  d_in[0];
  const float* embedding = (const float*)d_in[1];
  const float* w_ih_l0   = (const float*)d_in[2];
  const float* w_hh_l0   = (const float*)d_in[3];
  const float* b_ih_l0   = (const float*)d_in[4];
  const float* b_hh_l0   = (const float*)d_in[5];
  const float* w_ih_l0r  = (const float*)d_in[6];
  const float* w_hh_l0r  = (const float*)d_in[7];
  const float* b_ih_l0r  = (const float*)d_in[8];
  const float* b_hh_l0r  = (const float*)d_in[9];
  const float* w_ih_l1   = (const float*)d_in[10];
  const float* w_hh_l1   = (const float*)d_in[11];
  const float* b_ih_l1   = (const float*)d_in[12];
  const float* b_hh_l1   = (const float*)d_in[13];
  const float* w_ih_l1r  = (const float*)d_in[14];
  const float* w_hh_l1r  = (const float*)d_in[15];
  const float* b_ih_l1r  = (const float*)d_in[16];
  const float* b_hh_l1r  = (const float*)d_in[17];
  const float* h0        = (const float*)d_in[18];
  const float* c0        = (const float*)d_in[19];
  const float* W_tag     = (const float*)d_in[20];
  const float* b_tag     = (const float*)d_in[21];
  const float* trans     = (const float*)d_in[22];

  float* ws    = (float*)d_ws;
  float* pre_f = ws;                                  // [L][2048]
  float* pre_r = pre_f + (size_t)L_SEQ * NGATE4;      // [L][2048]
  float* l0out = pre_r + (size_t)L_SEQ * NGATE4;      // [L][1024]
  float* l1out = l0out + (size_t)L_SEQ * 1024;        // [L][1024]
  float* feats = l1out + (size_t)L_SEQ * 1024;        // [L][48]
  int*   slots = (int*)(feats + (size_t)L_SEQ * TAGS);// [2 layers][2][NWG]
  int*   bp    = slots + 4 * NWG;                     // [L][48]

  (void)hipMemsetAsync(slots, 0, 4 * NWG * sizeof(int), stream);

  dim3 blk(256);
  dim3 gfull(L_SEQ / BM, NGATE4 / BN);
  gemm_abt<<<gfull, blk, 0, stream>>>(embedding, w_ih_l0, b_ih_l0, b_hh_l0,
                                      pre_f, L_SEQ, NGATE4, 512, sentence);
  gemm_abt<<<gfull, blk, 0, stream>>>(embedding, w_ih_l0r, b_ih_l0r, b_hh_l0r,
                                      pre_r, L_SEQ, NGATE4, 512, sentence);
  lstm_layer<<<2 * NWG, 512, 0, stream>>>(pre_f, pre_r, w_hh_l0, w_hh_l0r,
                                          h0, c0, 0, l0out, slots);
  gemm_abt<<<gfull, blk, 0, stream>>>(l0out, w_ih_l1, b_ih_l1, b_hh_l1,
                                      pre_f, L_SEQ, NGATE4, 1024, nullptr);
  gemm_abt<<<gfull, blk, 0, stream>>>(l0out, w_ih_l1r, b_ih_l1r, b_hh_l1r,
                                      pre_r, L_SEQ, NGATE4, 1024, nullptr);
  lstm_layer<<<2 * NWG, 512, 0, stream>>>(pre_f, pre_r, w_hh_l1, w_hh_l1r,
                                          h0, c0, 2, l1out, slots + 2 * NWG);
  dim3 gfeat(L_SEQ / BM, 1);
  gemm_abt<<<gfeat, blk, 0, stream>>>(l1out, W_tag, b_tag, nullptr,
                                      feats, L_SEQ, TAGS, 1024, nullptr);
  viterbi_kernel<<<1, 192, 0, stream>>>(feats, trans, bp, (float*)d_out);
}

// Round 8
// 15065.518 us; speedup vs baseline: 1.6274x; 1.6274x over previous
//
#include <hip/hip_runtime.h>
#include <hip/hip_bf16.h>

#define L_SEQ 2048
#define HDIM 512
#define NGATE4 2048   // 4*HD
#define TAGS 48
#define START_TAG 46
#define STOP_TAG 47
#define NWG 32        // workgroups per direction in lstm_layer
#define JPW 16        // h-indices owned per WG

typedef float f32x4 __attribute__((ext_vector_type(4)));

// ---------------------------------------------------------------------------
// GEMM: C[M,N] = A[M,K] @ B[N,K]^T + bias1[n] (+ bias2[n])
// ---------------------------------------------------------------------------
#define BM 64
#define BN 64
#define BK 32
#define LDT 68   // padded LDS row stride (floats)

__global__ __launch_bounds__(256, 2)
void gemm_abt(const float* __restrict__ A, const float* __restrict__ B,
              const float* __restrict__ bias1, const float* __restrict__ bias2,
              float* __restrict__ C, int M, int N, int K,
              const int* __restrict__ gather)
{
  __shared__ float As[BK][LDT];
  __shared__ float Bs[BK][LDT];
  const int tid = threadIdx.x;
  const int m0 = blockIdx.x * BM;
  const int n0 = blockIdx.y * BN;
  const int tm = tid >> 4, tn = tid & 15;
  const int lr = tid >> 2, lk = (tid & 3) * 8;

  float acc[4][4];
#pragma unroll
  for (int i = 0; i < 4; ++i)
#pragma unroll
    for (int c = 0; c < 4; ++c) acc[i][c] = 0.f;

  const int am = m0 + lr;
  const float* arow = gather ? (A + (size_t)gather[am] * (size_t)K)
                             : (A + (size_t)am * (size_t)K);
  const int bn = n0 + lr;
  const float* brow = B + (size_t)bn * (size_t)K;
  const bool bok = (bn < N);

  for (int kt = 0; kt < K; kt += BK) {
    const float4 a0 = *(const float4*)(arow + kt + lk);
    const float4 a1 = *(const float4*)(arow + kt + lk + 4);
    float4 b0 = make_float4(0.f, 0.f, 0.f, 0.f);
    float4 b1 = make_float4(0.f, 0.f, 0.f, 0.f);
    if (bok) {
      b0 = *(const float4*)(brow + kt + lk);
      b1 = *(const float4*)(brow + kt + lk + 4);
    }
    As[lk + 0][lr] = a0.x; As[lk + 1][lr] = a0.y; As[lk + 2][lr] = a0.z; As[lk + 3][lr] = a0.w;
    As[lk + 4][lr] = a1.x; As[lk + 5][lr] = a1.y; As[lk + 6][lr] = a1.z; As[lk + 7][lr] = a1.w;
    Bs[lk + 0][lr] = b0.x; Bs[lk + 1][lr] = b0.y; Bs[lk + 2][lr] = b0.z; Bs[lk + 3][lr] = b0.w;
    Bs[lk + 4][lr] = b1.x; Bs[lk + 5][lr] = b1.y; Bs[lk + 6][lr] = b1.z; Bs[lk + 7][lr] = b1.w;
    __syncthreads();
#pragma unroll
    for (int kk = 0; kk < BK; ++kk) {
      const float4 av = *(const float4*)&As[kk][tm * 4];
      const float4 bv = *(const float4*)&Bs[kk][tn * 4];
      const float aa[4] = {av.x, av.y, av.z, av.w};
      const float bb[4] = {bv.x, bv.y, bv.z, bv.w};
#pragma unroll
      for (int i = 0; i < 4; ++i)
#pragma unroll
        for (int c = 0; c < 4; ++c)
          acc[i][c] += aa[i] * bb[c];
    }
    __syncthreads();
  }

  float bsum[4];
#pragma unroll
  for (int c = 0; c < 4; ++c) {
    const int n = n0 + tn * 4 + c;
    float bb = 0.f;
    if (n < N) { bb = bias1[n]; if (bias2) bb += bias2[n]; }
    bsum[c] = bb;
  }
#pragma unroll
  for (int i = 0; i < 4; ++i) {
    const int m = m0 + tm * 4 + i;
#pragma unroll
    for (int c = 0; c < 4; ++c) {
      const int n = n0 + tn * 4 + c;
      if (n < N) C[(size_t)m * N + n] = acc[i][c] + bsum[c];
    }
  }
}

// ---------------------------------------------------------------------------
// Persistent bidirectional LSTM layer — LDS-resident weights + single-hop
// packed-word handoff.
// 32 WGs x 512 threads per direction. WG owns 16 j; weights 16j x 4g x 512k
// f32 = 128 KB static LDS, lane-major (conflict-free ds_read_b128).
// Exchange: word = (bf16(h) << 16) | (layer_base + s + 1). One relaxed agent
// store per produced h; consumers poll their OWN word — data rides the tag
// load (no slots, one memory hop). 2-slot ring; tags layer-unique; xch
// memset(0) each launch. Thread map: wave -> 2 j's; lane = (g = lane>>4,
// q = lane&15, 32 k each); xor-shfl reduce over q; lane0 does cell update.
// ---------------------------------------------------------------------------
__global__ __launch_bounds__(512, 1)
void lstm_layer(const float* __restrict__ pre_f, const float* __restrict__ pre_r,
                const float* __restrict__ whh_f, const float* __restrict__ whh_r,
                const float* __restrict__ h0, const float* __restrict__ c0,
                int hcrow_base,
                float* __restrict__ hs_out,    // [L][1024] f32 (next GEMM)
                unsigned int* __restrict__ xch)// [2 slot][2 dir][512]
{
  const int dir = blockIdx.x & 1;
  const int wg  = blockIdx.x >> 1;          // 0..31
  const float* pre = dir ? pre_r : pre_f;
  const float* whh = dir ? whh_r : whh_f;
  const int tid = threadIdx.x;
  const int lane = tid & 63;
  const int wave = tid >> 6;                // 0..7
  const int q = lane & 15;                  // k-chunk (32 k)
  const int g = lane >> 4;                  // gate 0..3
  const int j0 = wg * JPW + wave * 2;       // this wave's two h indices
  const int hc = (hcrow_base + dir) * HDIM;
  const unsigned base = (unsigned)((hcrow_base >> 1) * 2048); // 0 | 2048

  __shared__ f32x4 wlds[8][2][8][64];       // [wave][jj][i][lane] = 128 KB
  __shared__ float h_lds[HDIM];

  // Stage weights lane-major; k-window rotated by q (h reads 2-way max).
#pragma unroll
  for (int jj = 0; jj < 2; ++jj) {
    const float* wr = whh + (size_t)(g * HDIM + j0 + jj) * HDIM + 32 * q;
#pragma unroll
    for (int i = 0; i < 8; ++i)
      wlds[wave][jj][i][lane] = *(const f32x4*)(wr + 4 * ((i + q) & 7));
  }
  h_lds[tid] = h0[hc + tid];
  float cA = 0.f, cB = 0.f;
  if (lane == 0) { cA = c0[hc + j0]; cB = c0[hc + j0 + 1]; }
  __syncthreads();

  // pre-activation prefetch at gate-leader lanes (q == 0)
  float pa = 0.f, pb = 0.f;
  if (q == 0) {
    const int t0 = dir ? (L_SEQ - 1) : 0;
    const float* pr = pre + (size_t)t0 * NGATE4 + g * HDIM + j0;
    pa = pr[0]; pb = pr[1];
  }

  for (int s = 0; s < L_SEQ; ++s) {
    const int t = dir ? (L_SEQ - 1 - s) : s;
    float pna = 0.f, pnb = 0.f;
    if (q == 0 && (s + 1 < L_SEQ)) {
      const int tnx = dir ? (L_SEQ - 2 - s) : (s + 1);
      const float* pr = pre + (size_t)tnx * NGATE4 + g * HDIM + j0;
      pna = pr[0]; pnb = pr[1];
    }

    f32x4 accA = {0.f, 0.f, 0.f, 0.f};
    f32x4 accB = {0.f, 0.f, 0.f, 0.f};
#pragma unroll
    for (int i = 0; i < 8; ++i) {
      const f32x4 hv = *(const f32x4*)&h_lds[32 * q + 4 * ((i + q) & 7)];
      accA += wlds[wave][0][i][lane] * hv;
      accB += wlds[wave][1][i][lane] * hv;
    }
    float aA = accA.x + accA.y + accA.z + accA.w;
    float aB = accB.x + accB.y + accB.z + accB.w;
#pragma unroll
    for (int m = 1; m < 16; m <<= 1) {     // reduce over q (lane bits 0-3)
      aA += __shfl_xor(aA, m, 64);
      aB += __shfl_xor(aB, m, 64);
    }
    aA += pa; aB += pb;                    // valid at q==0 lanes

    const float fA = __shfl(aA, 16, 64), gA = __shfl(aA, 32, 64), oA = __shfl(aA, 48, 64);
    const float fB = __shfl(aB, 16, 64), gB = __shfl(aB, 32, 64), oB = __shfl(aB, 48, 64);

    if (lane == 0) {
      const unsigned tag = base + (unsigned)s + 1u;
      const size_t ob = (size_t)t * 1024 + dir * HDIM + j0;
      unsigned* xp = xch + ((s + 1) & 1) * 1024 + dir * HDIM + j0;
      // j0
      {
        const float si = 1.f / (1.f + __expf(-aA));
        const float sf = 1.f / (1.f + __expf(-fA));
        const float tg = 1.f - 2.f / (__expf(2.f * gA) + 1.f);
        const float so = 1.f / (1.f + __expf(-oA));
        cA = sf * cA + si * tg;
        const float h = so * (1.f - 2.f / (__expf(2.f * cA) + 1.f));
        hs_out[ob] = h;
        unsigned u = __float_as_uint(h);
        u = (u + 0x7FFFu + ((u >> 16) & 1u)) & 0xFFFF0000u;  // RNE -> bf16 hi
        __hip_atomic_store(xp, u | tag, __ATOMIC_RELAXED, __HIP_MEMORY_SCOPE_AGENT);
      }
      // j0 + 1
      {
        const float si = 1.f / (1.f + __expf(-aB));
        const float sf = 1.f / (1.f + __expf(-fB));
        const float tg = 1.f - 2.f / (__expf(2.f * gB) + 1.f);
        const float so = 1.f / (1.f + __expf(-oB));
        cB = sf * cB + si * tg;
        const float h = so * (1.f - 2.f / (__expf(2.f * cB) + 1.f));
        hs_out[ob + 1] = h;
        unsigned u = __float_as_uint(h);
        u = (u + 0x7FFFu + ((u >> 16) & 1u)) & 0xFFFF0000u;
        __hip_atomic_store(xp + 1, u | tag, __ATOMIC_RELAXED, __HIP_MEMORY_SCOPE_AGENT);
      }
    }
    pa = pna; pb = pnb;

    if (s == L_SEQ - 1) break;

    __syncthreads();                       // all lanes done reading h_lds[s]
    {
      const unsigned expect = base + (unsigned)s + 1u;
      const unsigned* wp = xch + ((s + 1) & 1) * 1024 + dir * HDIM + tid;
      unsigned v;
      do {
        v = __hip_atomic_load(wp, __ATOMIC_RELAXED, __HIP_MEMORY_SCOPE_AGENT);
      } while ((v & 0xFFFFu) != expect);
      h_lds[tid] = __uint_as_float(v & 0xFFFF0000u);
    }
    __syncthreads();                       // h_lds[s+1] fully written
  }
}

// ---------------------------------------------------------------------------
// Viterbi: 1 WG, 192 threads = (48 tags) x (4 k-chunks of 12).
// ---------------------------------------------------------------------------
__global__ __launch_bounds__(192, 1)
void viterbi_kernel(const float* __restrict__ feats,
                    const float* __restrict__ trans,
                    int* __restrict__ bp,      // [L][48]
                    float* __restrict__ out)   // [1 + L]
{
  __shared__ float fv[TAGS];
  __shared__ float fvn[TAGS];
  const int tid = threadIdx.x;
  const int lane = tid & 63;
  const int wave = tid >> 6;
  const int q = lane & 3;
  const int j = wave * 16 + (lane >> 2);  // 0..47

  float trr[12];
#pragma unroll
  for (int kk = 0; kk < 12; ++kk) trr[kk] = trans[j * TAGS + q * 12 + kk];

  if (tid < TAGS) fv[tid] = (tid == START_TAG) ? 0.f : -10000.f;
  __syncthreads();

  for (int t = 0; t < L_SEQ; ++t) {
    const float ft = feats[t * TAGS + j];
    float best = -3.0e38f;
    int bi = 0;
#pragma unroll
    for (int kk = 0; kk < 12; ++kk) {
      const int k = q * 12 + kk;
      const float sc = fv[k] + trr[kk];
      if (sc > best) { best = sc; bi = k; }   // strict > keeps first max
    }
#pragma unroll
    for (int m = 1; m < 4; m <<= 1) {
      const float ov = __shfl_xor(best, m, 64);
      const int oi = __shfl_xor(bi, m, 64);
      if (ov > best || (ov == best && oi < bi)) { best = ov; bi = oi; }
    }
    __syncthreads();
    if (q == 0) {
      bp[t * TAGS + j] = bi;
      fv[j] = best + ft;
    }
    __syncthreads();
  }

  if (tid < TAGS) fvn[tid] = fv[tid] + trans[STOP_TAG * TAGS + tid];
  __syncthreads();
  if (tid == 0) {
    float best = -3.0e38f;
    int bi = 0;
    for (int k = 0; k < TAGS; ++k) {
      const float v = fvn[k];
      if (v > best) { best = v; bi = k; }
    }
    out[0] = best;
    int cur = bi;
    out[1 + (L_SEQ - 1)] = (float)cur;
    for (int t = L_SEQ - 2; t >= 0; --t) {
      cur = bp[(t + 1) * TAGS + cur];
      out[1 + t] = (float)cur;
    }
  }
}

// ---------------------------------------------------------------------------
extern "C" void kernel_launch(void* const* d_in, const int* in_sizes, int n_in,
                              void* d_out, int out_size, void* d_ws, size_t ws_size,
                              hipStream_t stream)
{
  const int*   sentence  = (const int*)  d_in[0];
  const float* embedding = (const float*)d_in[1];
  const float* w_ih_l0   = (const float*)d_in[2];
  const float* w_hh_l0   = (const float*)d_in[3];
  const float* b_ih_l0   = (const float*)d_in[4];
  const float* b_hh_l0   = (const float*)d_in[5];
  const float* w_ih_l0r  = (const float*)d_in[6];
  const float* w_hh_l0r  = (const float*)d_in[7];
  const float* b_ih_l0r  = (const float*)d_in[8];
  const float* b_hh_l0r  = (const float*)d_in[9];
  const float* w_ih_l1   = (const float*)d_in[10];
  const float* w_hh_l1   = (const float*)d_in[11];
  const float* b_ih_l1   = (const float*)d_in[12];
  const float* b_hh_l1   = (const float*)d_in[13];
  const float* w_ih_l1r  = (const float*)d_in[14];
  const float* w_hh_l1r  = (const float*)d_in[15];
  const float* b_ih_l1r  = (const float*)d_in[16];
  const float* b_hh_l1r  = (const float*)d_in[17];
  const float* h0        = (const float*)d_in[18];
  const float* c0        = (const float*)d_in[19];
  const float* W_tag     = (const float*)d_in[20];
  const float* b_tag     = (const float*)d_in[21];
  const float* trans     = (const float*)d_in[22];

  float* ws    = (float*)d_ws;
  float* pre_f = ws;                                  // [L][2048]
  float* pre_r = pre_f + (size_t)L_SEQ * NGATE4;      // [L][2048]
  float* l0out = pre_r + (size_t)L_SEQ * NGATE4;      // [L][1024]
  float* l1out = l0out + (size_t)L_SEQ * 1024;        // [L][1024]
  float* feats = l1out + (size_t)L_SEQ * 1024;        // [L][48]
  unsigned int* xch = (unsigned int*)(feats + (size_t)L_SEQ * TAGS); // [2][2][512]
  int*   bp    = (int*)(xch + 2048);                  // [L][48]

  (void)hipMemsetAsync(xch, 0, 2048 * sizeof(unsigned int), stream);

  dim3 blk(256);
  dim3 gfull(L_SEQ / BM, NGATE4 / BN);
  gemm_abt<<<gfull, blk, 0, stream>>>(embedding, w_ih_l0, b_ih_l0, b_hh_l0,
                                      pre_f, L_SEQ, NGATE4, 512, sentence);
  gemm_abt<<<gfull, blk, 0, stream>>>(embedding, w_ih_l0r, b_ih_l0r, b_hh_l0r,
                                      pre_r, L_SEQ, NGATE4, 512, sentence);
  lstm_layer<<<2 * NWG, 512, 0, stream>>>(pre_f, pre_r, w_hh_l0, w_hh_l0r,
                                          h0, c0, 0, l0out, xch);
  gemm_abt<<<gfull, blk, 0, stream>>>(l0out, w_ih_l1, b_ih_l1, b_hh_l1,
                                      pre_f, L_SEQ, NGATE4, 1024, nullptr);
  gemm_abt<<<gfull, blk, 0, stream>>>(l0out, w_ih_l1r, b_ih_l1r, b_hh_l1r,
                                      pre_r, L_SEQ, NGATE4, 1024, nullptr);
  lstm_layer<<<2 * NWG, 512, 0, stream>>>(pre_f, pre_r, w_hh_l1, w_hh_l1r,
                                          h0, c0, 2, l1out, xch);
  dim3 gfeat(L_SEQ / BM, 1);
  gemm_abt<<<gfeat, blk, 0, stream>>>(l1out, W_tag, b_tag, nullptr,
                                      feats, L_SEQ, TAGS, 1024, nullptr);
  viterbi_kernel<<<1, 192, 0, stream>>>(feats, trans, bp, (float*)d_out);
}